// Round 1
// baseline (402.106 us; speedup 1.0000x reference)
//
#include <hip/hip_runtime.h>

// Problem: FindInstancePeaks — fused conv backbone + global peak finding.
// crops (128,192,192,1) f32 -> conv1 3x3 s2 SAME (1->32) + relu
//                          -> conv2 3x3 s1 SAME (32->17) = cms (128,96,96,17)
// -> per (b,n): argmax over 96x96, quarter-pixel sign refinement, *2 stride,
//    NaN if val < 0.2. Output (128,17,3) f32.
//
// conv1 SAME (in=192,s=2,k=3): out=96, pad_total=1 -> pad_low=0, pad_high=1:
//   h(hy,hx) uses input rows 2hy..2hy+2 (row 192 zero-padded).
// conv2 SAME (in=96,s=1,k=3): pad 1 each side: cms(y,x) uses h rows y-1..y+1.

#define NCH 17
#define C1 32
#define TS 16          // cms tile
#define HT (TS + 2)    // 18 h rows/cols needed
#define HSTR 19        // padded col stride for s_h (odd -> no 2^k bank conflicts)
#define INT 37         // input patch: rows 2*(ty0-1) .. 2*(ty0+16)+2

__device__ __forceinline__ unsigned long long pack_key(float v, unsigned flat) {
    unsigned ub = __float_as_uint(v);
    ub = (ub & 0x80000000u) ? ~ub : (ub | 0x80000000u);   // monotone float->uint
    return ((unsigned long long)ub << 32) | (unsigned)(~flat); // ~flat: ties -> lowest idx
}

__global__ __launch_bounds__(256) void conv_peaks_kernel(
    const float* __restrict__ crops, const float* __restrict__ W1g,
    const float* __restrict__ b1g, const float* __restrict__ W2g,
    const float* __restrict__ b2g, unsigned long long* __restrict__ peaks) {
    __shared__ float s_in[INT * INT];          // 5.5 KB
    __shared__ float s_h[C1 * HT * HSTR];      // 43.8 KB, layout [c][row][col(19)]

    const int t = threadIdx.x;
    const int b = blockIdx.y;
    const int ty0 = (blockIdx.x / 6) * TS;
    const int tx0 = (blockIdx.x % 6) * TS;
    const int iy0 = 2 * ty0 - 2;
    const int ix0 = 2 * tx0 - 2;
    const float* cb = crops + b * 192 * 192;

    // --- stage input patch (zero-padded at image borders) ---
    for (int p = t; p < INT * INT; p += 256) {
        int r = p / INT, cc = p - r * INT;
        int iy = iy0 + r, ix = ix0 + cc;
        float v = 0.f;
        if (iy >= 0 && ix >= 0 && iy < 192 && ix < 192) v = cb[iy * 192 + ix];
        s_in[p] = v;
    }
    __syncthreads();

    // --- conv1 + relu into s_h; h outside [0,96) is conv2 zero-padding ---
    for (int p = t; p < HT * HT; p += 256) {
        int r = p / HT, cc = p - r * HT;
        int hy = ty0 - 1 + r, hx = tx0 - 1 + cc;
        bool valid = (hy >= 0) && (hy < 96) && (hx >= 0) && (hx < 96);
        float in9[9];
#pragma unroll
        for (int q = 0; q < 9; ++q)
            in9[q] = s_in[(2 * r + q / 3) * INT + (2 * cc + q % 3)];
#pragma unroll 4
        for (int n = 0; n < C1; ++n) {
            float a = b1g[n];                  // uniform -> s_load
#pragma unroll
            for (int q = 0; q < 9; ++q) a = fmaf(in9[q], W1g[q * C1 + n], a);
            a = valid ? fmaxf(a, 0.f) : 0.f;
            s_h[n * (HT * HSTR) + r * HSTR + cc] = a;
        }
    }
    __syncthreads();

    // --- conv2: one cms pixel per thread, 17 channels in registers ---
    const int ly = t >> 4, lx = t & 15;
    float acc[NCH];
#pragma unroll
    for (int n = 0; n < NCH; ++n) acc[n] = b2g[n];

#pragma unroll 1
    for (int k = 0; k < 9; ++k) {
        const int ky = k / 3, kx = k - ky * 3;
        const float* w2k = W2g + k * C1 * NCH;       // uniform -> s_load
        const float* hp = s_h + (ly + ky) * HSTR + (lx + kx);
#pragma unroll 4
        for (int c = 0; c < C1; ++c) {
            float hv = hp[c * (HT * HSTR)];          // 1 ds_read per 17 FMAs
            const float* w = w2k + c * NCH;
#pragma unroll
            for (int n = 0; n < NCH; ++n) acc[n] = fmaf(hv, w[n], acc[n]);
        }
    }

    // --- per-channel argmax: wave shuffle reduce + global atomicMax ---
    const int y = ty0 + ly, x = tx0 + lx;
    const unsigned flat = (unsigned)(y * 96 + x);
    const int lane = t & 63;
#pragma unroll 1
    for (int n = 0; n < NCH; ++n) {
        unsigned long long pk = pack_key(acc[n], flat);
#pragma unroll
        for (int off = 32; off; off >>= 1) {
            unsigned long long o = __shfl_down(pk, off, 64);
            if (o > pk) pk = o;
        }
        if (lane == 0) atomicMax(&peaks[b * NCH + n], pk);
    }
}

// One 64-lane wave per (b,n): decode peak, recompute 4 clipped neighbor cms
// values from crops (b2 bias cancels in differences), emit (x,y,val).
__global__ __launch_bounds__(64) void refine_kernel(
    const float* __restrict__ crops, const float* __restrict__ W1g,
    const float* __restrict__ b1g, const float* __restrict__ W2g,
    const unsigned long long* __restrict__ peaks, float* __restrict__ out) {
    const int bn = blockIdx.x;          // 0..128*17-1
    const int b = bn / NCH, n = bn % NCH;
    const int lane = threadIdx.x;

    unsigned long long pk = peaks[bn];
    unsigned key = (unsigned)(pk >> 32);
    unsigned fbits = (key & 0x80000000u) ? (key ^ 0x80000000u) : ~key;
    float val = __uint_as_float(fbits);
    int flat = (int)(~(unsigned)(pk & 0xffffffffu));
    int yi = flat / 96, xi = flat - yi * 96;

    // neighbor j: 0:(yi,xi+1) 1:(yi,xi-1) 2:(yi+1,xi) 3:(yi-1,xi), clipped
    const int j = lane >> 4;
    int yy = yi + ((j == 2) ? 1 : 0) - ((j == 3) ? 1 : 0);
    int xx = xi + ((j == 0) ? 1 : 0) - ((j == 1) ? 1 : 0);
    yy = min(max(yy, 0), 95);
    xx = min(max(xx, 0), 95);

    const float* cb = crops + b * 192 * 192;
    float part = 0.f;
#pragma unroll
    for (int ci = 0; ci < 2; ++ci) {
        const int c = (lane & 15) + ci * 16;
#pragma unroll 1
        for (int ky = 0; ky < 3; ++ky) {
#pragma unroll 1
            for (int kx = 0; kx < 3; ++kx) {
                int hy = yy + ky - 1, hx = xx + kx - 1;
                float hval = 0.f;
                if (hy >= 0 && hy < 96 && hx >= 0 && hx < 96) {
                    float a = b1g[c];
#pragma unroll
                    for (int q = 0; q < 9; ++q) {
                        int iy = 2 * hy + q / 3, ix = 2 * hx + q % 3;
                        float iv = (iy < 192 && ix < 192) ? cb[iy * 192 + ix] : 0.f;
                        a = fmaf(iv, W1g[(q / 3 * 3 + q % 3) * C1 + c], a);
                    }
                    hval = fmaxf(a, 0.f);
                }
                part = fmaf(hval, W2g[((ky * 3 + kx) * C1 + c) * NCH + n], part);
            }
        }
    }
    // sum the 16 lanes of each neighbor group
    for (int off = 8; off; off >>= 1) part += __shfl_down(part, off, 16);
    float g0 = __shfl(part, 0, 64);
    float g1 = __shfl(part, 16, 64);
    float g2 = __shfl(part, 32, 64);
    float g3 = __shfl(part, 48, 64);

    if (lane == 0) {
        float d0 = g0 - g1, d1 = g2 - g3;
        float sx = (d0 > 0.f) ? 1.f : ((d0 < 0.f) ? -1.f : 0.f);
        float sy = (d1 > 0.f) ? 1.f : ((d1 < 0.f) ? -1.f : 0.f);
        float px = ((float)xi + 0.25f * sx) * 2.f;
        float py = ((float)yi + 0.25f * sy) * 2.f;
        if (!(val >= 0.2f)) {
            px = __int_as_float(0x7fc00000);
            py = __int_as_float(0x7fc00000);
        }
        out[bn * 3 + 0] = px;
        out[bn * 3 + 1] = py;
        out[bn * 3 + 2] = val;
    }
}

extern "C" void kernel_launch(void* const* d_in, const int* in_sizes, int n_in,
                              void* d_out, int out_size, void* d_ws, size_t ws_size,
                              hipStream_t stream) {
    const float* crops = (const float*)d_in[0];
    const float* W1 = (const float*)d_in[1];
    const float* b1 = (const float*)d_in[2];
    const float* W2 = (const float*)d_in[3];
    const float* b2 = (const float*)d_in[4];
    float* out = (float*)d_out;
    unsigned long long* peaks = (unsigned long long*)d_ws;

    hipMemsetAsync(d_ws, 0, 128 * NCH * sizeof(unsigned long long), stream);

    dim3 gridB(36, 128);  // 6x6 tiles of 16x16 over 96x96, per image
    conv_peaks_kernel<<<gridB, 256, 0, stream>>>(crops, W1, b1, W2, b2, peaks);
    refine_kernel<<<128 * NCH, 64, 0, stream>>>(crops, W1, b1, W2, peaks, out);
}

// Round 2
// 294.195 us; speedup vs baseline: 1.3668x; 1.3668x over previous
//
#include <hip/hip_runtime.h>

// FindInstancePeaks: fused conv backbone + global peak finding.
// crops (128,192,192,1) f32 -> conv1 3x3 s2 SAME (1->32) + relu
//                          -> conv2 3x3 s1 SAME (32->17) = cms (128,96,96,17)
// -> per (b,n): argmax over 96x96, quarter-pixel sign refine, *2, NaN<0.2.
//
// R2: 32x32 tile, 4 px/thread (68 accs), conv1 split into 8 passes of 4
// channels; W2 slice staged in LDS so the conv2 hot loop is DS-only
// (no s_load/ds_read lgkmcnt mixing). LDS 40532 B -> 4 blocks/CU.

#define NCH 17
#define C1 32
#define TS2 32          // cms tile (32x32)
#define HT2 34          // h rows/cols needed (tile+2)
#define HSTR2 35        // s_h col stride
#define IN2 69          // input patch: 2*32+5
#define CG 4            // conv1 channels per group
#define NG 8            // groups

__device__ __forceinline__ unsigned long long pack_key(float v, unsigned flat) {
    unsigned ub = __float_as_uint(v);
    ub = (ub & 0x80000000u) ? ~ub : (ub | 0x80000000u);   // monotone float->uint
    return ((unsigned long long)ub << 32) | (unsigned)(~flat); // ~flat: ties -> lowest idx
}

__global__ __launch_bounds__(256, 4) void conv_peaks_kernel(
    const float* __restrict__ crops, const float* __restrict__ W1g,
    const float* __restrict__ b1g, const float* __restrict__ W2g,
    const float* __restrict__ b2g, unsigned long long* __restrict__ peaks) {
    __shared__ float s_in[IN2 * IN2];                       // 19044 B
    __shared__ float s_h[CG * HT2 * HSTR2];                 // 19040 B
    __shared__ __align__(16) float s_w2[9 * CG * 16];       // 2304 B (n=0..15)
    __shared__ float s_w2t[9 * CG];                         // 144 B  (n=16)

    const int t = threadIdx.x;
    const int b = blockIdx.y;
    const int ty0 = (blockIdx.x / 3) * TS2;
    const int tx0 = (blockIdx.x % 3) * TS2;
    const int iy0 = 2 * ty0 - 2;
    const int ix0 = 2 * tx0 - 2;
    const float* cb = crops + b * 192 * 192;

    // --- stage input patch (zero-padded at image borders) ---
    for (int p = t; p < IN2 * IN2; p += 256) {
        int r = p / IN2, cc = p - r * IN2;
        int iy = iy0 + r, ix = ix0 + cc;
        float v = 0.f;
        if (iy >= 0 && ix >= 0 && iy < 192 && ix < 192) v = cb[iy * 192 + ix];
        s_in[p] = v;
    }

    const int ly = t >> 4, lx = t & 15;
    float acc0[NCH], acc1[NCH], acc2[NCH], acc3[NCH];
#pragma unroll
    for (int n = 0; n < NCH; ++n) { acc0[n] = 0.f; acc1[n] = 0.f; acc2[n] = 0.f; acc3[n] = 0.f; }

#pragma unroll 1
    for (int g = 0; g < NG; ++g) {
        __syncthreads();   // staging / previous conv2 done before overwriting LDS

        // stage W2 slice for this channel group
        for (int p = t; p < 9 * CG * NCH; p += 256) {
            int k = p / (CG * NCH);
            int rem = p - k * (CG * NCH);
            int cl = rem / NCH, n = rem - cl * NCH;
            float w = W2g[(k * C1 + (g * CG + cl)) * NCH + n];
            if (n < 16) s_w2[(k * CG + cl) * 16 + n] = w;
            else        s_w2t[k * CG + cl] = w;
        }

        // conv1 + relu for this group's 4 channels
        for (int p = t; p < HT2 * HT2; p += 256) {
            int r = p / HT2, cc = p - r * HT2;
            int hy = ty0 - 1 + r, hx = tx0 - 1 + cc;
            bool valid = (hy >= 0) && (hy < 96) && (hx >= 0) && (hx < 96);
            float in9[9];
#pragma unroll
            for (int q = 0; q < 9; ++q)
                in9[q] = s_in[(2 * r + q / 3) * IN2 + (2 * cc + q % 3)];
#pragma unroll
            for (int cl = 0; cl < CG; ++cl) {
                int c = g * CG + cl;
                float a = b1g[c];
#pragma unroll
                for (int q = 0; q < 9; ++q) a = fmaf(in9[q], W1g[q * C1 + c], a);
                a = valid ? fmaxf(a, 0.f) : 0.f;
                s_h[cl * (HT2 * HSTR2) + r * HSTR2 + cc] = a;
            }
        }
        __syncthreads();

        // conv2 partial: 4 pixels/thread, DS-only inner loop
#pragma unroll 1
        for (int k = 0; k < 9; ++k) {
            const int ky = k / 3, kx = k - ky * 3;
            const int hb = (ly + ky) * HSTR2 + (lx + kx);
#pragma unroll 1
            for (int cl = 0; cl < CG; ++cl) {
                const float* hpp = s_h + cl * (HT2 * HSTR2) + hb;
                float hv0 = hpp[0];
                float hv1 = hpp[16];
                float hv2 = hpp[16 * HSTR2];
                float hv3 = hpp[16 * HSTR2 + 16];
                const float4* wp = (const float4*)(s_w2 + (k * CG + cl) * 16);
                float4 w0 = wp[0], w1 = wp[1], w2 = wp[2], w3 = wp[3];
                float wt = s_w2t[k * CG + cl];
                float wv;
#define STEP(NI, WV) wv = (WV); \
                acc0[NI] = fmaf(hv0, wv, acc0[NI]); \
                acc1[NI] = fmaf(hv1, wv, acc1[NI]); \
                acc2[NI] = fmaf(hv2, wv, acc2[NI]); \
                acc3[NI] = fmaf(hv3, wv, acc3[NI]);
                STEP(0, w0.x)  STEP(1, w0.y)  STEP(2, w0.z)  STEP(3, w0.w)
                STEP(4, w1.x)  STEP(5, w1.y)  STEP(6, w1.z)  STEP(7, w1.w)
                STEP(8, w2.x)  STEP(9, w2.y)  STEP(10, w2.z) STEP(11, w2.w)
                STEP(12, w3.x) STEP(13, w3.y) STEP(14, w3.z) STEP(15, w3.w)
                STEP(16, wt)
#undef STEP
            }
        }
    }

    // --- per-channel argmax: in-thread max over 4 px, then wave reduce ---
    const int y0 = ty0 + ly, x0 = tx0 + lx;
    const unsigned f0 = (unsigned)(y0 * 96 + x0);
    const unsigned f1 = (unsigned)(y0 * 96 + x0 + 16);
    const unsigned f2 = (unsigned)((y0 + 16) * 96 + x0);
    const unsigned f3 = (unsigned)((y0 + 16) * 96 + x0 + 16);
    const int lane = t & 63;
#pragma unroll 1
    for (int n = 0; n < NCH; ++n) {
        float bb = b2g[n];
        unsigned long long pk = pack_key(acc0[n] + bb, f0);
        unsigned long long o1 = pack_key(acc1[n] + bb, f1);
        unsigned long long o2 = pack_key(acc2[n] + bb, f2);
        unsigned long long o3 = pack_key(acc3[n] + bb, f3);
        if (o1 > pk) pk = o1;
        if (o2 > pk) pk = o2;
        if (o3 > pk) pk = o3;
#pragma unroll
        for (int off = 32; off; off >>= 1) {
            unsigned long long o = __shfl_down(pk, off, 64);
            if (o > pk) pk = o;
        }
        if (lane == 0) atomicMax(&peaks[b * NCH + n], pk);
    }
}

// One 64-lane wave per (b,n): decode peak, recompute 4 clipped neighbor cms
// values from crops (b2 bias cancels in differences), emit (x,y,val).
__global__ __launch_bounds__(64) void refine_kernel(
    const float* __restrict__ crops, const float* __restrict__ W1g,
    const float* __restrict__ b1g, const float* __restrict__ W2g,
    const unsigned long long* __restrict__ peaks, float* __restrict__ out) {
    const int bn = blockIdx.x;          // 0..128*17-1
    const int b = bn / NCH, n = bn % NCH;
    const int lane = threadIdx.x;

    unsigned long long pk = peaks[bn];
    unsigned key = (unsigned)(pk >> 32);
    unsigned fbits = (key & 0x80000000u) ? (key ^ 0x80000000u) : ~key;
    float val = __uint_as_float(fbits);
    int flat = (int)(~(unsigned)(pk & 0xffffffffu));
    int yi = flat / 96, xi = flat - yi * 96;

    // neighbor j: 0:(yi,xi+1) 1:(yi,xi-1) 2:(yi+1,xi) 3:(yi-1,xi), clipped
    const int j = lane >> 4;
    int yy = yi + ((j == 2) ? 1 : 0) - ((j == 3) ? 1 : 0);
    int xx = xi + ((j == 0) ? 1 : 0) - ((j == 1) ? 1 : 0);
    yy = min(max(yy, 0), 95);
    xx = min(max(xx, 0), 95);

    const float* cb = crops + b * 192 * 192;
    float part = 0.f;
#pragma unroll
    for (int ci = 0; ci < 2; ++ci) {
        const int c = (lane & 15) + ci * 16;
#pragma unroll 1
        for (int ky = 0; ky < 3; ++ky) {
#pragma unroll 1
            for (int kx = 0; kx < 3; ++kx) {
                int hy = yy + ky - 1, hx = xx + kx - 1;
                float hval = 0.f;
                if (hy >= 0 && hy < 96 && hx >= 0 && hx < 96) {
                    float a = b1g[c];
#pragma unroll
                    for (int q = 0; q < 9; ++q) {
                        int iy = 2 * hy + q / 3, ix = 2 * hx + q % 3;
                        float iv = (iy < 192 && ix < 192) ? cb[iy * 192 + ix] : 0.f;
                        a = fmaf(iv, W1g[(q / 3 * 3 + q % 3) * C1 + c], a);
                    }
                    hval = fmaxf(a, 0.f);
                }
                part = fmaf(hval, W2g[((ky * 3 + kx) * C1 + c) * NCH + n], part);
            }
        }
    }
    // sum the 16 lanes of each neighbor group
    for (int off = 8; off; off >>= 1) part += __shfl_down(part, off, 16);
    float g0 = __shfl(part, 0, 64);
    float g1 = __shfl(part, 16, 64);
    float g2 = __shfl(part, 32, 64);
    float g3 = __shfl(part, 48, 64);

    if (lane == 0) {
        float d0 = g0 - g1, d1 = g2 - g3;
        float sx = (d0 > 0.f) ? 1.f : ((d0 < 0.f) ? -1.f : 0.f);
        float sy = (d1 > 0.f) ? 1.f : ((d1 < 0.f) ? -1.f : 0.f);
        float px = ((float)xi + 0.25f * sx) * 2.f;
        float py = ((float)yi + 0.25f * sy) * 2.f;
        if (!(val >= 0.2f)) {
            px = __int_as_float(0x7fc00000);
            py = __int_as_float(0x7fc00000);
        }
        out[bn * 3 + 0] = px;
        out[bn * 3 + 1] = py;
        out[bn * 3 + 2] = val;
    }
}

extern "C" void kernel_launch(void* const* d_in, const int* in_sizes, int n_in,
                              void* d_out, int out_size, void* d_ws, size_t ws_size,
                              hipStream_t stream) {
    const float* crops = (const float*)d_in[0];
    const float* W1 = (const float*)d_in[1];
    const float* b1 = (const float*)d_in[2];
    const float* W2 = (const float*)d_in[3];
    const float* b2 = (const float*)d_in[4];
    float* out = (float*)d_out;
    unsigned long long* peaks = (unsigned long long*)d_ws;

    hipMemsetAsync(d_ws, 0, 128 * NCH * sizeof(unsigned long long), stream);

    dim3 gridB(9, 128);   // 3x3 tiles of 32x32 over 96x96, per image
    conv_peaks_kernel<<<gridB, 256, 0, stream>>>(crops, W1, b1, W2, b2, peaks);
    refine_kernel<<<128 * NCH, 64, 0, stream>>>(crops, W1, b1, W2, peaks, out);
}

// Round 3
// 264.075 us; speedup vs baseline: 1.5227x; 1.1141x over previous
//
#include <hip/hip_runtime.h>

// FindInstancePeaks: fused conv backbone + global peak finding.
// crops (128,192,192,1) f32 -> conv1 3x3 s2 SAME (1->32) + relu
//                          -> conv2 3x3 s1 SAME (32->17) = cms (128,96,96,17)
// -> per (b,n): argmax over 96x96, quarter-pixel sign refine, *2, NaN<0.2.
//
// R3: same structure as R2 (32x32 tile, 4 px/thread, 8 channel groups,
// W2 slice in LDS, DS-only conv2 inner loop) but the final argmax loop is
// FULLY UNROLLED: R2's `#pragma unroll 1` + acc0[n] dynamic indexing forced
// all 68 accumulators into scratch (VGPR_Count 52, WRITE_SIZE 263 MB).
// Full unroll -> SROA keeps accs in VGPRs.

#define NCH 17
#define C1 32
#define TS2 32          // cms tile (32x32)
#define HT2 34          // h rows/cols needed (tile+2)
#define HSTR2 35        // s_h col stride
#define IN2 69          // input patch: 2*32+5
#define CG 4            // conv1 channels per group
#define NG 8            // groups

__device__ __forceinline__ unsigned long long pack_key(float v, unsigned flat) {
    unsigned ub = __float_as_uint(v);
    ub = (ub & 0x80000000u) ? ~ub : (ub | 0x80000000u);   // monotone float->uint
    return ((unsigned long long)ub << 32) | (unsigned)(~flat); // ~flat: ties -> lowest idx
}

__global__ __launch_bounds__(256, 4) void conv_peaks_kernel(
    const float* __restrict__ crops, const float* __restrict__ W1g,
    const float* __restrict__ b1g, const float* __restrict__ W2g,
    const float* __restrict__ b2g, unsigned long long* __restrict__ peaks) {
    __shared__ float s_in[IN2 * IN2];                       // 19044 B
    __shared__ float s_h[CG * HT2 * HSTR2];                 // 19040 B
    __shared__ __align__(16) float s_w2[9 * CG * 16];       // 2304 B (n=0..15)
    __shared__ float s_w2t[9 * CG];                         // 144 B  (n=16)

    const int t = threadIdx.x;
    const int b = blockIdx.y;
    const int ty0 = (blockIdx.x / 3) * TS2;
    const int tx0 = (blockIdx.x % 3) * TS2;
    const int iy0 = 2 * ty0 - 2;
    const int ix0 = 2 * tx0 - 2;
    const float* cb = crops + b * 192 * 192;

    // --- stage input patch (zero-padded at image borders) ---
    for (int p = t; p < IN2 * IN2; p += 256) {
        int r = p / IN2, cc = p - r * IN2;
        int iy = iy0 + r, ix = ix0 + cc;
        float v = 0.f;
        if (iy >= 0 && ix >= 0 && iy < 192 && ix < 192) v = cb[iy * 192 + ix];
        s_in[p] = v;
    }

    const int ly = t >> 4, lx = t & 15;
    float acc0[NCH], acc1[NCH], acc2[NCH], acc3[NCH];
#pragma unroll
    for (int n = 0; n < NCH; ++n) { acc0[n] = 0.f; acc1[n] = 0.f; acc2[n] = 0.f; acc3[n] = 0.f; }

#pragma unroll 1
    for (int g = 0; g < NG; ++g) {
        __syncthreads();   // staging / previous conv2 done before overwriting LDS

        // stage W2 slice for this channel group
        for (int p = t; p < 9 * CG * NCH; p += 256) {
            int k = p / (CG * NCH);
            int rem = p - k * (CG * NCH);
            int cl = rem / NCH, n = rem - cl * NCH;
            float w = W2g[(k * C1 + (g * CG + cl)) * NCH + n];
            if (n < 16) s_w2[(k * CG + cl) * 16 + n] = w;
            else        s_w2t[k * CG + cl] = w;
        }

        // conv1 + relu for this group's 4 channels
        for (int p = t; p < HT2 * HT2; p += 256) {
            int r = p / HT2, cc = p - r * HT2;
            int hy = ty0 - 1 + r, hx = tx0 - 1 + cc;
            bool valid = (hy >= 0) && (hy < 96) && (hx >= 0) && (hx < 96);
            float in9[9];
#pragma unroll
            for (int q = 0; q < 9; ++q)
                in9[q] = s_in[(2 * r + q / 3) * IN2 + (2 * cc + q % 3)];
#pragma unroll
            for (int cl = 0; cl < CG; ++cl) {
                int c = g * CG + cl;
                float a = b1g[c];
#pragma unroll
                for (int q = 0; q < 9; ++q) a = fmaf(in9[q], W1g[q * C1 + c], a);
                a = valid ? fmaxf(a, 0.f) : 0.f;
                s_h[cl * (HT2 * HSTR2) + r * HSTR2 + cc] = a;
            }
        }
        __syncthreads();

        // conv2 partial: 4 pixels/thread, DS-only inner loop
#pragma unroll 1
        for (int k = 0; k < 9; ++k) {
            const int ky = k / 3, kx = k - ky * 3;
            const int hb = (ly + ky) * HSTR2 + (lx + kx);
#pragma unroll 1
            for (int cl = 0; cl < CG; ++cl) {
                const float* hpp = s_h + cl * (HT2 * HSTR2) + hb;
                float hv0 = hpp[0];
                float hv1 = hpp[16];
                float hv2 = hpp[16 * HSTR2];
                float hv3 = hpp[16 * HSTR2 + 16];
                const float4* wp = (const float4*)(s_w2 + (k * CG + cl) * 16);
                float4 w0 = wp[0], w1 = wp[1], w2 = wp[2], w3 = wp[3];
                float wt = s_w2t[k * CG + cl];
                float wv;
#define STEP(NI, WV) wv = (WV); \
                acc0[NI] = fmaf(hv0, wv, acc0[NI]); \
                acc1[NI] = fmaf(hv1, wv, acc1[NI]); \
                acc2[NI] = fmaf(hv2, wv, acc2[NI]); \
                acc3[NI] = fmaf(hv3, wv, acc3[NI]);
                STEP(0, w0.x)  STEP(1, w0.y)  STEP(2, w0.z)  STEP(3, w0.w)
                STEP(4, w1.x)  STEP(5, w1.y)  STEP(6, w1.z)  STEP(7, w1.w)
                STEP(8, w2.x)  STEP(9, w2.y)  STEP(10, w2.z) STEP(11, w2.w)
                STEP(12, w3.x) STEP(13, w3.y) STEP(14, w3.z) STEP(15, w3.w)
                STEP(16, wt)
#undef STEP
            }
        }
    }

    // --- per-channel argmax: in-thread max over 4 px, then wave reduce ---
    // FULLY unrolled (constant indices) so acc arrays stay in registers.
    const int y0 = ty0 + ly, x0 = tx0 + lx;
    const unsigned f0 = (unsigned)(y0 * 96 + x0);
    const unsigned f1 = (unsigned)(y0 * 96 + x0 + 16);
    const unsigned f2 = (unsigned)((y0 + 16) * 96 + x0);
    const unsigned f3 = (unsigned)((y0 + 16) * 96 + x0 + 16);
    const int lane = t & 63;
#pragma unroll
    for (int n = 0; n < NCH; ++n) {
        float bb = b2g[n];
        unsigned long long pk = pack_key(acc0[n] + bb, f0);
        unsigned long long o1 = pack_key(acc1[n] + bb, f1);
        unsigned long long o2 = pack_key(acc2[n] + bb, f2);
        unsigned long long o3 = pack_key(acc3[n] + bb, f3);
        if (o1 > pk) pk = o1;
        if (o2 > pk) pk = o2;
        if (o3 > pk) pk = o3;
#pragma unroll
        for (int off = 32; off; off >>= 1) {
            unsigned long long o = __shfl_down(pk, off, 64);
            if (o > pk) pk = o;
        }
        if (lane == 0) atomicMax(&peaks[b * NCH + n], pk);
    }
}

// One 64-lane wave per (b,n): decode peak, recompute 4 clipped neighbor cms
// values from crops (b2 bias cancels in differences), emit (x,y,val).
__global__ __launch_bounds__(64) void refine_kernel(
    const float* __restrict__ crops, const float* __restrict__ W1g,
    const float* __restrict__ b1g, const float* __restrict__ W2g,
    const unsigned long long* __restrict__ peaks, float* __restrict__ out) {
    const int bn = blockIdx.x;          // 0..128*17-1
    const int b = bn / NCH, n = bn % NCH;
    const int lane = threadIdx.x;

    unsigned long long pk = peaks[bn];
    unsigned key = (unsigned)(pk >> 32);
    unsigned fbits = (key & 0x80000000u) ? (key ^ 0x80000000u) : ~key;
    float val = __uint_as_float(fbits);
    int flat = (int)(~(unsigned)(pk & 0xffffffffu));
    int yi = flat / 96, xi = flat - yi * 96;

    // neighbor j: 0:(yi,xi+1) 1:(yi,xi-1) 2:(yi+1,xi) 3:(yi-1,xi), clipped
    const int j = lane >> 4;
    int yy = yi + ((j == 2) ? 1 : 0) - ((j == 3) ? 1 : 0);
    int xx = xi + ((j == 0) ? 1 : 0) - ((j == 1) ? 1 : 0);
    yy = min(max(yy, 0), 95);
    xx = min(max(xx, 0), 95);

    const float* cb = crops + b * 192 * 192;
    float part = 0.f;
#pragma unroll
    for (int ci = 0; ci < 2; ++ci) {
        const int c = (lane & 15) + ci * 16;
#pragma unroll 1
        for (int ky = 0; ky < 3; ++ky) {
#pragma unroll 1
            for (int kx = 0; kx < 3; ++kx) {
                int hy = yy + ky - 1, hx = xx + kx - 1;
                float hval = 0.f;
                if (hy >= 0 && hy < 96 && hx >= 0 && hx < 96) {
                    float a = b1g[c];
#pragma unroll
                    for (int q = 0; q < 9; ++q) {
                        int iy = 2 * hy + q / 3, ix = 2 * hx + q % 3;
                        float iv = (iy < 192 && ix < 192) ? cb[iy * 192 + ix] : 0.f;
                        a = fmaf(iv, W1g[(q / 3 * 3 + q % 3) * C1 + c], a);
                    }
                    hval = fmaxf(a, 0.f);
                }
                part = fmaf(hval, W2g[((ky * 3 + kx) * C1 + c) * NCH + n], part);
            }
        }
    }
    // sum the 16 lanes of each neighbor group
    for (int off = 8; off; off >>= 1) part += __shfl_down(part, off, 16);
    float g0 = __shfl(part, 0, 64);
    float g1 = __shfl(part, 16, 64);
    float g2 = __shfl(part, 32, 64);
    float g3 = __shfl(part, 48, 64);

    if (lane == 0) {
        float d0 = g0 - g1, d1 = g2 - g3;
        float sx = (d0 > 0.f) ? 1.f : ((d0 < 0.f) ? -1.f : 0.f);
        float sy = (d1 > 0.f) ? 1.f : ((d1 < 0.f) ? -1.f : 0.f);
        float px = ((float)xi + 0.25f * sx) * 2.f;
        float py = ((float)yi + 0.25f * sy) * 2.f;
        if (!(val >= 0.2f)) {
            px = __int_as_float(0x7fc00000);
            py = __int_as_float(0x7fc00000);
        }
        out[bn * 3 + 0] = px;
        out[bn * 3 + 1] = py;
        out[bn * 3 + 2] = val;
    }
}

extern "C" void kernel_launch(void* const* d_in, const int* in_sizes, int n_in,
                              void* d_out, int out_size, void* d_ws, size_t ws_size,
                              hipStream_t stream) {
    const float* crops = (const float*)d_in[0];
    const float* W1 = (const float*)d_in[1];
    const float* b1 = (const float*)d_in[2];
    const float* W2 = (const float*)d_in[3];
    const float* b2 = (const float*)d_in[4];
    float* out = (float*)d_out;
    unsigned long long* peaks = (unsigned long long*)d_ws;

    hipMemsetAsync(d_ws, 0, 128 * NCH * sizeof(unsigned long long), stream);

    dim3 gridB(9, 128);   // 3x3 tiles of 32x32 over 96x96, per image
    conv_peaks_kernel<<<gridB, 256, 0, stream>>>(crops, W1, b1, W2, b2, peaks);
    refine_kernel<<<128 * NCH, 64, 0, stream>>>(crops, W1, b1, W2, peaks, out);
}

// Round 4
// 263.453 us; speedup vs baseline: 1.5263x; 1.0024x over previous
//
#include <hip/hip_runtime.h>

// FindInstancePeaks: fused conv backbone + global peak finding.
// crops (128,192,192,1) f32 -> conv1 3x3 s2 SAME (1->32) + relu
//                          -> conv2 3x3 s1 SAME (32->17) = cms (128,96,96,17)
// -> per (b,n): argmax over 96x96, quarter-pixel sign refine, *2, NaN<0.2.
//
// R4: R3's counters (VGPR=52 with 68 live accs, no HBM spill, dur ~= 3x FMA
// floor) say the allocator parked accumulators in AGPRs under the 128-reg
// launch_bounds(256,4) budget -> accvgpr_read/fma/accvgpr_write per STEP.
// Fix: (a) launch_bounds(256,3) -> 168-reg budget, accs in arch VGPRs;
// (b) v_pk_fma_f32: acc as float2 pairs (px0,px1)/(px2,px3), hv via
// ds_read2_b32, scalar weight broadcast via op_sel -> half the instructions.

#define NCH 17
#define C1 32
#define TS2 32          // cms tile (32x32)
#define HT2 34          // h rows/cols needed (tile+2)
#define HSTR2 35        // s_h col stride
#define IN2 69          // input patch: 2*32+5
#define CG 4            // conv1 channels per group
#define NG 8            // groups

typedef float v2f __attribute__((ext_vector_type(2)));

__device__ __forceinline__ unsigned long long pack_key(float v, unsigned flat) {
    unsigned ub = __float_as_uint(v);
    ub = (ub & 0x80000000u) ? ~ub : (ub | 0x80000000u);   // monotone float->uint
    return ((unsigned long long)ub << 32) | (unsigned)(~flat); // ~flat: ties -> lowest idx
}

__global__ __launch_bounds__(256, 3) void conv_peaks_kernel(
    const float* __restrict__ crops, const float* __restrict__ W1g,
    const float* __restrict__ b1g, const float* __restrict__ W2g,
    const float* __restrict__ b2g, unsigned long long* __restrict__ peaks) {
    __shared__ float s_in[IN2 * IN2];                       // 19044 B
    __shared__ float s_h[CG * HT2 * HSTR2];                 // 19040 B
    __shared__ __align__(16) float s_w2[9 * CG * 16];       // 2304 B (n=0..15)
    __shared__ float s_w2t[9 * CG];                         // 144 B  (n=16)

    const int t = threadIdx.x;
    const int b = blockIdx.y;
    const int ty0 = (blockIdx.x / 3) * TS2;
    const int tx0 = (blockIdx.x % 3) * TS2;
    const int iy0 = 2 * ty0 - 2;
    const int ix0 = 2 * tx0 - 2;
    const float* cb = crops + b * 192 * 192;

    // --- stage input patch (zero-padded at image borders) ---
    for (int p = t; p < IN2 * IN2; p += 256) {
        int r = p / IN2, cc = p - r * IN2;
        int iy = iy0 + r, ix = ix0 + cc;
        float v = 0.f;
        if (iy >= 0 && ix >= 0 && iy < 192 && ix < 192) v = cb[iy * 192 + ix];
        s_in[p] = v;
    }

    const int ly = t >> 4, lx = t & 15;
    v2f accA[NCH], accB[NCH];   // A: (px0,px1) = (y,x),(y,x+16); B: +16 rows
#pragma unroll
    for (int n = 0; n < NCH; ++n) { accA[n] = (v2f)(0.f); accB[n] = (v2f)(0.f); }

#pragma unroll 1
    for (int g = 0; g < NG; ++g) {
        __syncthreads();   // staging / previous conv2 done before overwriting LDS

        // stage W2 slice for this channel group
        for (int p = t; p < 9 * CG * NCH; p += 256) {
            int k = p / (CG * NCH);
            int rem = p - k * (CG * NCH);
            int cl = rem / NCH, n = rem - cl * NCH;
            float w = W2g[(k * C1 + (g * CG + cl)) * NCH + n];
            if (n < 16) s_w2[(k * CG + cl) * 16 + n] = w;
            else        s_w2t[k * CG + cl] = w;
        }

        // conv1 + relu for this group's 4 channels
        for (int p = t; p < HT2 * HT2; p += 256) {
            int r = p / HT2, cc = p - r * HT2;
            int hy = ty0 - 1 + r, hx = tx0 - 1 + cc;
            bool valid = (hy >= 0) && (hy < 96) && (hx >= 0) && (hx < 96);
            float in9[9];
#pragma unroll
            for (int q = 0; q < 9; ++q)
                in9[q] = s_in[(2 * r + q / 3) * IN2 + (2 * cc + q % 3)];
#pragma unroll
            for (int cl = 0; cl < CG; ++cl) {
                int c = g * CG + cl;
                float a = b1g[c];
#pragma unroll
                for (int q = 0; q < 9; ++q) a = fmaf(in9[q], W1g[q * C1 + c], a);
                a = valid ? fmaxf(a, 0.f) : 0.f;
                s_h[cl * (HT2 * HSTR2) + r * HSTR2 + cc] = a;
            }
        }
        __syncthreads();

        // conv2 partial: 4 pixels/thread as 2 pk-pairs, DS-only inner loop
#pragma unroll 1
        for (int k = 0; k < 9; ++k) {
            const int ky = k / 3, kx = k - ky * 3;
            const int hb = (ly + ky) * HSTR2 + (lx + kx);
#pragma unroll 1
            for (int cl = 0; cl < CG; ++cl) {
                const float* hpp = s_h + cl * (HT2 * HSTR2) + hb;
                v2f hA, hB;                    // -> ds_read2_b32
                hA.x = hpp[0];
                hA.y = hpp[16];
                hB.x = hpp[16 * HSTR2];
                hB.y = hpp[16 * HSTR2 + 16];
                const float4* wp = (const float4*)(s_w2 + (k * CG + cl) * 16);
                float4 w0 = wp[0], w1 = wp[1], w2 = wp[2], w3 = wp[3];
                float wt = s_w2t[k * CG + cl];
#define STEP(NI, WV) { v2f wv2; wv2.x = (WV); wv2.y = (WV); \
                accA[NI] = __builtin_elementwise_fma(hA, wv2, accA[NI]); \
                accB[NI] = __builtin_elementwise_fma(hB, wv2, accB[NI]); }
                STEP(0, w0.x)  STEP(1, w0.y)  STEP(2, w0.z)  STEP(3, w0.w)
                STEP(4, w1.x)  STEP(5, w1.y)  STEP(6, w1.z)  STEP(7, w1.w)
                STEP(8, w2.x)  STEP(9, w2.y)  STEP(10, w2.z) STEP(11, w2.w)
                STEP(12, w3.x) STEP(13, w3.y) STEP(14, w3.z) STEP(15, w3.w)
                STEP(16, wt)
#undef STEP
            }
        }
    }

    // --- per-channel argmax: in-thread max over 4 px, then wave reduce ---
    // Fully unrolled (constant indices) so acc arrays stay in registers.
    const int y0 = ty0 + ly, x0 = tx0 + lx;
    const unsigned f0 = (unsigned)(y0 * 96 + x0);
    const unsigned f1 = (unsigned)(y0 * 96 + x0 + 16);
    const unsigned f2 = (unsigned)((y0 + 16) * 96 + x0);
    const unsigned f3 = (unsigned)((y0 + 16) * 96 + x0 + 16);
    const int lane = t & 63;
#pragma unroll
    for (int n = 0; n < NCH; ++n) {
        float bb = b2g[n];
        unsigned long long pk = pack_key(accA[n].x + bb, f0);
        unsigned long long o1 = pack_key(accA[n].y + bb, f1);
        unsigned long long o2 = pack_key(accB[n].x + bb, f2);
        unsigned long long o3 = pack_key(accB[n].y + bb, f3);
        if (o1 > pk) pk = o1;
        if (o2 > pk) pk = o2;
        if (o3 > pk) pk = o3;
#pragma unroll
        for (int off = 32; off; off >>= 1) {
            unsigned long long o = __shfl_down(pk, off, 64);
            if (o > pk) pk = o;
        }
        if (lane == 0) atomicMax(&peaks[b * NCH + n], pk);
    }
}

// One 64-lane wave per (b,n): decode peak, recompute 4 clipped neighbor cms
// values from crops (b2 bias cancels in differences), emit (x,y,val).
__global__ __launch_bounds__(64) void refine_kernel(
    const float* __restrict__ crops, const float* __restrict__ W1g,
    const float* __restrict__ b1g, const float* __restrict__ W2g,
    const unsigned long long* __restrict__ peaks, float* __restrict__ out) {
    const int bn = blockIdx.x;          // 0..128*17-1
    const int b = bn / NCH, n = bn % NCH;
    const int lane = threadIdx.x;

    unsigned long long pk = peaks[bn];
    unsigned key = (unsigned)(pk >> 32);
    unsigned fbits = (key & 0x80000000u) ? (key ^ 0x80000000u) : ~key;
    float val = __uint_as_float(fbits);
    int flat = (int)(~(unsigned)(pk & 0xffffffffu));
    int yi = flat / 96, xi = flat - yi * 96;

    // neighbor j: 0:(yi,xi+1) 1:(yi,xi-1) 2:(yi+1,xi) 3:(yi-1,xi), clipped
    const int j = lane >> 4;
    int yy = yi + ((j == 2) ? 1 : 0) - ((j == 3) ? 1 : 0);
    int xx = xi + ((j == 0) ? 1 : 0) - ((j == 1) ? 1 : 0);
    yy = min(max(yy, 0), 95);
    xx = min(max(xx, 0), 95);

    const float* cb = crops + b * 192 * 192;
    float part = 0.f;
#pragma unroll
    for (int ci = 0; ci < 2; ++ci) {
        const int c = (lane & 15) + ci * 16;
#pragma unroll 1
        for (int ky = 0; ky < 3; ++ky) {
#pragma unroll 1
            for (int kx = 0; kx < 3; ++kx) {
                int hy = yy + ky - 1, hx = xx + kx - 1;
                float hval = 0.f;
                if (hy >= 0 && hy < 96 && hx >= 0 && hx < 96) {
                    float a = b1g[c];
#pragma unroll
                    for (int q = 0; q < 9; ++q) {
                        int iy = 2 * hy + q / 3, ix = 2 * hx + q % 3;
                        float iv = (iy < 192 && ix < 192) ? cb[iy * 192 + ix] : 0.f;
                        a = fmaf(iv, W1g[(q / 3 * 3 + q % 3) * C1 + c], a);
                    }
                    hval = fmaxf(a, 0.f);
                }
                part = fmaf(hval, W2g[((ky * 3 + kx) * C1 + c) * NCH + n], part);
            }
        }
    }
    // sum the 16 lanes of each neighbor group
    for (int off = 8; off; off >>= 1) part += __shfl_down(part, off, 16);
    float g0 = __shfl(part, 0, 64);
    float g1 = __shfl(part, 16, 64);
    float g2 = __shfl(part, 32, 64);
    float g3 = __shfl(part, 48, 64);

    if (lane == 0) {
        float d0 = g0 - g1, d1 = g2 - g3;
        float sx = (d0 > 0.f) ? 1.f : ((d0 < 0.f) ? -1.f : 0.f);
        float sy = (d1 > 0.f) ? 1.f : ((d1 < 0.f) ? -1.f : 0.f);
        float px = ((float)xi + 0.25f * sx) * 2.f;
        float py = ((float)yi + 0.25f * sy) * 2.f;
        if (!(val >= 0.2f)) {
            px = __int_as_float(0x7fc00000);
            py = __int_as_float(0x7fc00000);
        }
        out[bn * 3 + 0] = px;
        out[bn * 3 + 1] = py;
        out[bn * 3 + 2] = val;
    }
}

extern "C" void kernel_launch(void* const* d_in, const int* in_sizes, int n_in,
                              void* d_out, int out_size, void* d_ws, size_t ws_size,
                              hipStream_t stream) {
    const float* crops = (const float*)d_in[0];
    const float* W1 = (const float*)d_in[1];
    const float* b1 = (const float*)d_in[2];
    const float* W2 = (const float*)d_in[3];
    const float* b2 = (const float*)d_in[4];
    float* out = (float*)d_out;
    unsigned long long* peaks = (unsigned long long*)d_ws;

    hipMemsetAsync(d_ws, 0, 128 * NCH * sizeof(unsigned long long), stream);

    dim3 gridB(9, 128);   // 3x3 tiles of 32x32 over 96x96, per image
    conv_peaks_kernel<<<gridB, 256, 0, stream>>>(crops, W1, b1, W2, b2, peaks);
    refine_kernel<<<128 * NCH, 64, 0, stream>>>(crops, W1, b1, W2, peaks, out);
}

// Round 5
// 229.311 us; speedup vs baseline: 1.7535x; 1.1489x over previous
//
#include <hip/hip_runtime.h>

// FindInstancePeaks: fused conv backbone + global peak finding.
// crops (128,192,192,1) f32 -> conv1 3x3 s2 SAME (1->32) + relu
//                          -> conv2 3x3 s1 SAME (32->17) = cms (128,96,96,17)
// -> per (b,n): argmax over 96x96, quarter-pixel sign refine, *2, NaN<0.2.
//
// R5: R3/R4 counters show the CU LDS pipe is the bottleneck (per-wave
// conv2 LDS ~77 cyc vs 39 cyc VALU share; 22k LDS cyc/wave * 18 waves/CU
// ~= 190us ~= measured). Restructure conv2 so LDS nearly vanishes:
//  - thread owns 4 CONTIGUOUS x pixels; per cl, 3 h-rows x 6 floats are
//    loaded once (ds_read_b128+b64, 6 insts) and serve 612 FMAs;
//  - W2 read via wave-uniform s_load from global (SMEM pipe, zero LDS),
//    17 contiguous floats per (k,cl) -> dwordx8-vectorizable;
//  - accumulators live happily in AGPRs (gfx950 VALU addresses AGPRs
//    directly - R4 showed zero cost).

#define NCH 17
#define C1 32
#define TS2 32          // cms tile (32x32)
#define HT2 34          // h rows/cols needed (tile+2)
#define HS 36           // s_h col stride (floats): 144 B rows, 16B-aligned
#define IN2 69          // input patch: 2*32+5
#define CG 4            // conv1 channels per group
#define NG 8            // groups

__device__ __forceinline__ unsigned long long pack_key(float v, unsigned flat) {
    unsigned ub = __float_as_uint(v);
    ub = (ub & 0x80000000u) ? ~ub : (ub | 0x80000000u);   // monotone float->uint
    return ((unsigned long long)ub << 32) | (unsigned)(~flat); // ~flat: ties -> lowest idx
}

__global__ __launch_bounds__(256, 3) void conv_peaks_kernel(
    const float* __restrict__ crops, const float* __restrict__ W1g,
    const float* __restrict__ b1g, const float* __restrict__ W2g,
    const float* __restrict__ b2g, unsigned long long* __restrict__ peaks) {
    __shared__ float s_in[IN2 * IN2];                        // 19044 B
    __shared__ __align__(16) float s_h[CG * HT2 * HS];       // 19584 B

    const int t = threadIdx.x;
    const int b = blockIdx.y;
    const int ty0 = (blockIdx.x / 3) * TS2;
    const int tx0 = (blockIdx.x % 3) * TS2;
    const int iy0 = 2 * ty0 - 2;
    const int ix0 = 2 * tx0 - 2;
    const float* cb = crops + b * 192 * 192;

    // --- stage input patch (zero-padded at image borders) ---
    for (int p = t; p < IN2 * IN2; p += 256) {
        int r = p / IN2, cc = p - r * IN2;
        int iy = iy0 + r, ix = ix0 + cc;
        float v = 0.f;
        if (iy >= 0 && ix >= 0 && iy < 192 && ix < 192) v = cb[iy * 192 + ix];
        s_in[p] = v;
    }

    // thread -> 4 contiguous pixels: row ly, cols lx0..lx0+3
    const int ly = t >> 3;            // 0..31
    const int lx0 = (t & 7) * 4;      // 0,4,...,28
    float acc[NCH][4];
#pragma unroll
    for (int n = 0; n < NCH; ++n)
#pragma unroll
        for (int p = 0; p < 4; ++p) acc[n][p] = 0.f;

#pragma unroll 1
    for (int g = 0; g < NG; ++g) {
        __syncthreads();   // prev conv2 reads / staging done before overwrite

        // conv1 + relu for this group's 4 channels
        for (int p = t; p < HT2 * HT2; p += 256) {
            int r = p / HT2, cc = p - r * HT2;
            int hy = ty0 - 1 + r, hx = tx0 - 1 + cc;
            bool valid = (hy >= 0) && (hy < 96) && (hx >= 0) && (hx < 96);
            float in9[9];
#pragma unroll
            for (int q = 0; q < 9; ++q)
                in9[q] = s_in[(2 * r + q / 3) * IN2 + (2 * cc + q % 3)];
#pragma unroll
            for (int cl = 0; cl < CG; ++cl) {
                int c = g * CG + cl;
                float a = b1g[c];
#pragma unroll
                for (int q = 0; q < 9; ++q) a = fmaf(in9[q], W1g[q * C1 + c], a);
                a = valid ? fmaxf(a, 0.f) : 0.f;
                s_h[cl * (HT2 * HS) + r * HS + cc] = a;
            }
        }
        __syncthreads();

        // conv2 partial: per cl, load 3 h-rows x 6 floats once (LDS), read
        // W2 via uniform s_load (SMEM), then 612 register-only FMAs.
#pragma unroll 1
        for (int cl = 0; cl < CG; ++cl) {
            float hrow[3][6];
            const float* hp = s_h + cl * (HT2 * HS) + ly * HS + lx0;
#pragma unroll
            for (int r = 0; r < 3; ++r) {
                float4 h4 = *(const float4*)(hp + r * HS);       // ds_read_b128
                float2 h2 = *(const float2*)(hp + r * HS + 4);   // ds_read_b64
                hrow[r][0] = h4.x; hrow[r][1] = h4.y;
                hrow[r][2] = h4.z; hrow[r][3] = h4.w;
                hrow[r][4] = h2.x; hrow[r][5] = h2.y;
            }
            const int c = g * CG + cl;
#pragma unroll
            for (int k = 0; k < 9; ++k) {
                const int ky = k / 3, kx = k - ky * 3;
                const float* wb = W2g + (k * C1 + c) * NCH;  // uniform -> s_load
                float w[NCH];
#pragma unroll
                for (int n = 0; n < NCH; ++n) w[n] = wb[n];
#pragma unroll
                for (int n = 0; n < NCH; ++n)
#pragma unroll
                    for (int p = 0; p < 4; ++p)
                        acc[n][p] = fmaf(hrow[ky][kx + p], w[n], acc[n][p]);
            }
        }
    }

    // --- per-channel argmax: in-thread max over 4 px, then wave reduce ---
    const int yg = ty0 + ly, xg = tx0 + lx0;
    const int lane = t & 63;
#pragma unroll
    for (int n = 0; n < NCH; ++n) {
        float bb = b2g[n];
        unsigned long long pk = pack_key(acc[n][0] + bb, (unsigned)(yg * 96 + xg));
#pragma unroll
        for (int p = 1; p < 4; ++p) {
            unsigned long long o = pack_key(acc[n][p] + bb, (unsigned)(yg * 96 + xg + p));
            if (o > pk) pk = o;
        }
#pragma unroll
        for (int off = 32; off; off >>= 1) {
            unsigned long long o = __shfl_down(pk, off, 64);
            if (o > pk) pk = o;
        }
        if (lane == 0) atomicMax(&peaks[b * NCH + n], pk);
    }
}

// One 64-lane wave per (b,n): decode peak, recompute 4 clipped neighbor cms
// values from crops (b2 bias cancels in differences), emit (x,y,val).
__global__ __launch_bounds__(64) void refine_kernel(
    const float* __restrict__ crops, const float* __restrict__ W1g,
    const float* __restrict__ b1g, const float* __restrict__ W2g,
    const unsigned long long* __restrict__ peaks, float* __restrict__ out) {
    const int bn = blockIdx.x;          // 0..128*17-1
    const int b = bn / NCH, n = bn % NCH;
    const int lane = threadIdx.x;

    unsigned long long pk = peaks[bn];
    unsigned key = (unsigned)(pk >> 32);
    unsigned fbits = (key & 0x80000000u) ? (key ^ 0x80000000u) : ~key;
    float val = __uint_as_float(fbits);
    int flat = (int)(~(unsigned)(pk & 0xffffffffu));
    int yi = flat / 96, xi = flat - yi * 96;

    // neighbor j: 0:(yi,xi+1) 1:(yi,xi-1) 2:(yi+1,xi) 3:(yi-1,xi), clipped
    const int j = lane >> 4;
    int yy = yi + ((j == 2) ? 1 : 0) - ((j == 3) ? 1 : 0);
    int xx = xi + ((j == 0) ? 1 : 0) - ((j == 1) ? 1 : 0);
    yy = min(max(yy, 0), 95);
    xx = min(max(xx, 0), 95);

    const float* cb = crops + b * 192 * 192;
    float part = 0.f;
#pragma unroll
    for (int ci = 0; ci < 2; ++ci) {
        const int c = (lane & 15) + ci * 16;
#pragma unroll 1
        for (int ky = 0; ky < 3; ++ky) {
#pragma unroll 1
            for (int kx = 0; kx < 3; ++kx) {
                int hy = yy + ky - 1, hx = xx + kx - 1;
                float hval = 0.f;
                if (hy >= 0 && hy < 96 && hx >= 0 && hx < 96) {
                    float a = b1g[c];
#pragma unroll
                    for (int q = 0; q < 9; ++q) {
                        int iy = 2 * hy + q / 3, ix = 2 * hx + q % 3;
                        float iv = (iy < 192 && ix < 192) ? cb[iy * 192 + ix] : 0.f;
                        a = fmaf(iv, W1g[(q / 3 * 3 + q % 3) * C1 + c], a);
                    }
                    hval = fmaxf(a, 0.f);
                }
                part = fmaf(hval, W2g[((ky * 3 + kx) * C1 + c) * NCH + n], part);
            }
        }
    }
    // sum the 16 lanes of each neighbor group
    for (int off = 8; off; off >>= 1) part += __shfl_down(part, off, 16);
    float g0 = __shfl(part, 0, 64);
    float g1 = __shfl(part, 16, 64);
    float g2 = __shfl(part, 32, 64);
    float g3 = __shfl(part, 48, 64);

    if (lane == 0) {
        float d0 = g0 - g1, d1 = g2 - g3;
        float sx = (d0 > 0.f) ? 1.f : ((d0 < 0.f) ? -1.f : 0.f);
        float sy = (d1 > 0.f) ? 1.f : ((d1 < 0.f) ? -1.f : 0.f);
        float px = ((float)xi + 0.25f * sx) * 2.f;
        float py = ((float)yi + 0.25f * sy) * 2.f;
        if (!(val >= 0.2f)) {
            px = __int_as_float(0x7fc00000);
            py = __int_as_float(0x7fc00000);
        }
        out[bn * 3 + 0] = px;
        out[bn * 3 + 1] = py;
        out[bn * 3 + 2] = val;
    }
}

extern "C" void kernel_launch(void* const* d_in, const int* in_sizes, int n_in,
                              void* d_out, int out_size, void* d_ws, size_t ws_size,
                              hipStream_t stream) {
    const float* crops = (const float*)d_in[0];
    const float* W1 = (const float*)d_in[1];
    const float* b1 = (const float*)d_in[2];
    const float* W2 = (const float*)d_in[3];
    const float* b2 = (const float*)d_in[4];
    float* out = (float*)d_out;
    unsigned long long* peaks = (unsigned long long*)d_ws;

    hipMemsetAsync(d_ws, 0, 128 * NCH * sizeof(unsigned long long), stream);

    dim3 gridB(9, 128);   // 3x3 tiles of 32x32 over 96x96, per image
    conv_peaks_kernel<<<gridB, 256, 0, stream>>>(crops, W1, b1, W2, b2, peaks);
    refine_kernel<<<128 * NCH, 64, 0, stream>>>(crops, W1, b1, W2, peaks, out);
}